// Round 6
// baseline (664.488 us; speedup 1.0000x reference)
//
#include <hip/hip_runtime.h>

#define HID 128
#define NE 250000
#define NT 3
#define NN 50000
#define NSEG (NT * NN)          // 150000 segments (type-major)
#define BPAD 136                // LDS W row stride in halves (272B: 16B-aligned, 2-way banks)
#define PLANE (NN * 256)        // u16 elems per combined plane (512 B rows)
#define SCHUNK 147              // 1024 * 147 = 150528 >= NSEG

typedef unsigned int u32;
typedef unsigned short u16;
typedef __attribute__((ext_vector_type(8))) short short8;
typedef __attribute__((ext_vector_type(4))) float f32x4;

__device__ __forceinline__ u16 f2bf(float f) {
    u32 u = __float_as_uint(f);
    u += 0x7fffu + ((u >> 16) & 1u);      // RNE, inputs finite
    return (u16)(u >> 16);
}
__device__ __forceinline__ float bflo(u32 u) { return __uint_as_float(u << 16); }
__device__ __forceinline__ float bfhi(u32 u) { return __uint_as_float(u & 0xffff0000u); }

// ---- prep: xbf convert | W transpose+convert | CSR degree count, one dispatch
__global__ __launch_bounds__(256)
void prep_kernel(const float* __restrict__ x,
                 const float* __restrict__ Wq, const float* __restrict__ Wk,
                 const float* __restrict__ Wm,
                 u16* __restrict__ Xbf, u16* __restrict__ Wtb,
                 const int* __restrict__ a0, const int* __restrict__ a1,
                 const int* __restrict__ a2, u32* __restrict__ counts)
{
    const int b = blockIdx.x, tid = threadIdx.x;
    if (b < 6250) {                       // x -> bf16, 1,600,000 float4 exactly
        const int gid = b * 256 + tid;
        const float4 v = ((const float4*)x)[gid];
        ushort4 o;
        o.x = f2bf(v.x); o.y = f2bf(v.y); o.z = f2bf(v.z); o.w = f2bf(v.w);
        ((ushort4*)Xbf)[gid] = o;
    } else if (b < 7018) {                // W -> Wtb[mat][n][k] bf16, 196,608 exactly
        const int gid = (b - 6250) * 256 + tid;
        const int mat = gid >> 14;
        const int i   = gid & 16383;      // i = k*128 + n
        const int k   = i >> 7;
        const int n   = i & 127;
        const int t   = mat >> 2;
        const int m   = mat & 3;
        const float* src;
        if (m == 0)      src = Wq + (size_t)t * 16384;
        else if (m == 1) src = Wk + (size_t)t * 16384;
        else if (m == 2) src = Wm + (size_t)t * 32768;
        else             src = Wm + (size_t)t * 32768 + 16384;
        Wtb[(size_t)mat * 16384 + n * HID + k] = f2bf(src[i]);
    } else {                              // degree count
        const int gid = (b - 7018) * 256 + tid;
        if (gid >= NT * NE) return;
        const int t = gid / NE, e = gid - t * NE;
        const int* adj = (t == 0) ? a0 : (t == 1) ? a1 : a2;
        atomicAdd(&counts[t * NN + adj[2 * e + 1]], 1u);
    }
}

// ---- single-block exclusive scan over NSEG counts -> offsets & cursors
__global__ __launch_bounds__(1024)
void scan_kernel(const u32* __restrict__ counts, u32* __restrict__ offsets,
                 u32* __restrict__ cursors)
{
    __shared__ u32 s[1024];
    const int t  = threadIdx.x;
    const int lo = t * SCHUNK;
    const int hi = min(lo + SCHUNK, NSEG);
    u32 sum = 0;
    for (int i = lo; i < hi; ++i) sum += counts[i];
    s[t] = sum;
    __syncthreads();
    for (int st = 1; st < 1024; st <<= 1) {          // Hillis-Steele inclusive
        const u32 a = (t >= st) ? s[t - st] : 0u;
        __syncthreads();
        s[t] += a;
        __syncthreads();
    }
    u32 run = s[t] - sum;                             // exclusive base for this chunk
    for (int i = lo; i < hi; ++i) {
        const u32 c = counts[i];
        offsets[i] = run;
        cursors[i] = run;
        run += c;
    }
}

__global__ __launch_bounds__(256)
void scatter_kernel(const int* __restrict__ a0, const int* __restrict__ a1,
                    const int* __restrict__ a2, u32* __restrict__ cursors,
                    u32* __restrict__ edata)
{
    const int gid = blockIdx.x * 256 + threadIdx.x;
    if (gid >= NT * NE) return;
    const int t = gid / NE, e = gid - t * NE;
    const int* adj = (t == 0) ? a0 : (t == 1) ? a1 : a2;
    const int src = adj[2 * e];
    const int tgt = adj[2 * e + 1];
    const u32 pos = atomicAdd(&cursors[t * NN + tgt], 1u);
    edata[pos] = (u32)src;
}

// ---- MFMA gemm, transposed orientation: D = W^T (A) x X^T (B)
// C/D: n=lane&15 -> node, row=quad*4+reg -> outcol => lane holds 4 consecutive
// outcols of ONE node. Interleaved plane layout: node row = 512 B, group g holds
// {slot0: cols 2g,2g+1 of k|q, slot1: cols 2g,2g+1 of a|b} as 2 u32s.
__global__ __launch_bounds__(256)
void gemm_kernel(const u16* __restrict__ Xbf, const u16* __restrict__ Wtb,
                 const float* __restrict__ bm, u16* __restrict__ P,
                 int tbase, int fusedF)
{
    __shared__ u16 Ws[128 * BPAD];        // 34,816 B
    const int tid = threadIdx.x;
    const int by  = blockIdx.y;
    const int mat = tbase * 4 + by;
    const int t   = mat >> 2, m = mat & 3;
    const u16* Wt = Wtb + (size_t)mat * 16384;

    for (int c = tid; c < 2048; c += 256) {
        const int r = c >> 4, s = (c & 15) * 8;
        *(short8*)&Ws[r * BPAD + s] = *(const short8*)(Wt + r * HID + s);
    }
    __syncthreads();

    const int wave = tid >> 6, lane = tid & 63;
    const int lm = lane & 15, quad = lane >> 4;
    const int r0 = blockIdx.x * 128 + wave * 32;
    const int ar0 = min(r0 + lm,      NN - 1);   // clamp; stores guarded
    const int ar1 = min(r0 + 16 + lm, NN - 1);

    f32x4 acc[8][2];
    #pragma unroll
    for (int ct = 0; ct < 8; ++ct) {
        acc[ct][0] = (f32x4){0.f, 0.f, 0.f, 0.f};
        acc[ct][1] = (f32x4){0.f, 0.f, 0.f, 0.f};
    }

    for (int k0 = 0; k0 < HID; k0 += 32) {
        // B-frag (X^T): n=node=lane&15, k=quad*8+j -> contiguous in Xbf[node]
        const short8 X0 = *(const short8*)(Xbf + (size_t)ar0 * HID + k0 + quad * 8);
        const short8 X1 = *(const short8*)(Xbf + (size_t)ar1 * HID + k0 + quad * 8);
        #pragma unroll
        for (int ct = 0; ct < 8; ++ct) {
            // A-frag (W^T): m=outcol=lane&15, k=quad*8+j -> contiguous in Wtb[n][k]
            const short8 Wf = *(const short8*)&Ws[(ct * 16 + lm) * BPAD + k0 + quad * 8];
            acc[ct][0] = __builtin_amdgcn_mfma_f32_16x16x32_bf16(Wf, X0, acc[ct][0], 0, 0, 0);
            acc[ct][1] = __builtin_amdgcn_mfma_f32_16x16x32_bf16(Wf, X1, acc[ct][1], 0, 0, 0);
        }
    }

    const int slot = (m == 2 || m == 3) ? 2 : 0;                   // a,b -> slot 1
    const int pidx = (m == 1 || m == 2) ? (fusedF ? t : 0)         // KA plane
                                        : (fusedF ? (3 + t) : 1);  // QB plane
    u16* Pd = P + (size_t)pidx * PLANE + slot;
    #pragma unroll
    for (int ct = 0; ct < 8; ++ct) {
        const int oc = ct * 16 + quad * 4;           // this lane's 4 outcols
        const int g0 = oc >> 1;                      // group of (oc,oc+1)
        float b0 = 0.f, b1 = 0.f, b2 = 0.f, b3 = 0.f;
        if (m == 3) {
            const float4 bv = *(const float4*)(bm + t * HID + oc);
            b0 = bv.x; b1 = bv.y; b2 = bv.z; b3 = bv.w;
        }
        #pragma unroll
        for (int nt = 0; nt < 2; ++nt) {
            const int node = r0 + nt * 16 + lm;
            if (node < NN) {
                u16* rowp = Pd + (size_t)node * 256;
                *(u32*)(rowp + g0 * 4) =
                    (u32)f2bf(acc[ct][nt][0] + b0) | ((u32)f2bf(acc[ct][nt][1] + b1) << 16);
                *(u32*)(rowp + (g0 + 1) * 4) =
                    (u32)f2bf(acc[ct][nt][2] + b2) | ((u32)f2bf(acc[ct][nt][3] + b3) << 16);
            }
        }
    }
}

// ---- gather: one wave per node; loops ntypes types, acc/den in registers.
// mode: 0 = accumulate (RMW out + sumexp), 1 = final using sumexp, 2 = final pure
__global__ __launch_bounds__(256)
void gather_kernel(const u16* __restrict__ P, const u32* __restrict__ offsets,
                   const u32* __restrict__ counts, const u32* __restrict__ edata,
                   float* __restrict__ out, float* __restrict__ sumexp,
                   int tbase, int ntypes, int mode, int fusedF)
{
    const int wave = threadIdx.x >> 6, lane = threadIdx.x & 63;
    const int node = blockIdx.x * 4 + wave;
    if (node >= NN) return;
    const int h = lane >> 3;

    float acc0 = 0.f, acc1 = 0.f, den = 0.f;
    int degtot = 0;

    for (int tt = 0; tt < ntypes; ++tt) {
        const u16* KA = P + (size_t)(fusedF ? tt : 0) * PLANE;
        const u16* QB = P + (size_t)(fusedF ? (3 + tt) : 1) * PLANE;
        const int seg   = (tbase + tt) * NN + node;
        const u32 start = offsets[seg];
        const int deg   = (int)counts[seg];
        degtot += deg;
        if (deg == 0) continue;

        const uint2 qbv = *(const uint2*)(QB + (size_t)node * 256 + lane * 4);
        const float q0 = bflo(qbv.x) * 0.25f, q1 = bfhi(qbv.x) * 0.25f;  // fold PHD^-0.5
        const float b0 = bflo(qbv.y), b1 = bfhi(qbv.y);

        for (int e = 0; e < deg; e += 4) {           // clamped-tail uniform loop
            uint2 kav[4];
            float w[4];
            #pragma unroll
            for (int u = 0; u < 4; ++u) {
                const int idx = min(e + u, deg - 1);
                const int src = __builtin_amdgcn_readfirstlane((int)edata[start + idx]);
                kav[u] = *(const uint2*)(KA + (size_t)src * 256 + lane * 4);
                w[u] = (e + u < deg) ? 1.f : 0.f;
            }
            #pragma unroll
            for (int u = 0; u < 4; ++u) {
                float d = q0 * bflo(kav[u].x) + q1 * bfhi(kav[u].x);
                d += __shfl_xor(d, 1);
                d += __shfl_xor(d, 2);
                d += __shfl_xor(d, 4);
                const float ex = __expf(d) * w[u];
                acc0 += ex * fmaxf(bflo(kav[u].y) + b0, 0.f);
                acc1 += ex * fmaxf(bfhi(kav[u].y) + b1, 0.f);
                den  += ex;
            }
        }
    }

    float* op = out + (size_t)node * HID + lane * 2;
    if (mode == 2) {                       // fused: softmax over all 3 types in-register
        const float inv = den > 0.f ? 1.f / den : 0.f;
        float2 o;
        o.x = acc0 * inv;
        o.y = acc1 * inv;
        *(float2*)op = o;
    } else if (mode == 1) {
        const float tot = sumexp[(size_t)node * 8 + h] + den;
        const float inv = tot > 0.f ? 1.f / tot : 0.f;
        float2 o = *(float2*)op;
        o.x = (o.x + acc0) * inv;
        o.y = (o.y + acc1) * inv;
        *(float2*)op = o;
    } else {
        if (degtot == 0) return;
        float2 o = *(float2*)op;
        o.x += acc0; o.y += acc1;
        *(float2*)op = o;
        if ((lane & 7) == 0) sumexp[(size_t)node * 8 + h] += den;
    }
}

extern "C" void kernel_launch(void* const* d_in, const int* in_sizes, int n_in,
                              void* d_out, int out_size, void* d_ws, size_t ws_size,
                              hipStream_t stream)
{
    const float* x  = (const float*)d_in[0];
    const int* a0   = (const int*)d_in[1];
    const int* a1   = (const int*)d_in[2];
    const int* a2   = (const int*)d_in[3];
    const float* Wq = (const float*)d_in[4];
    const float* Wk = (const float*)d_in[5];
    const float* Wm = (const float*)d_in[6];
    const float* bm = (const float*)d_in[7];
    float* out = (float*)d_out;

    // ws layout; fused path: 6 combined planes (153.6 MB), fallback: 2 (51.2 MB).
    const size_t planeB = (size_t)PLANE * sizeof(u16);       // 25.6 MB
    const size_t fixedB = 12800000 + 393216 + 3 * 600000 + 3000000 + 1600000;
    const int fused = (ws_size >= 6 * planeB + fixedB) ? 1 : 0;
    const int npl = fused ? 6 : 2;

    char* p = (char*)d_ws;
    u16* P        = (u16*)p;            p += (size_t)npl * planeB;
    u16* Xbf      = (u16*)p;            p += 12800000;
    u16* Wtb      = (u16*)p;            p += 393216;
    u32* counts   = (u32*)p;            p += 600000;
    u32* offsets  = (u32*)p;            p += 600000;
    u32* cursors  = (u32*)p;            p += 600000;
    u32* edata    = (u32*)p;            p += 3000000;
    float* sumexp = (float*)p;

    hipMemsetAsync(counts, 0, (size_t)NSEG * sizeof(u32), stream);
    if (!fused) {
        hipMemsetAsync(out,    0, (size_t)NN * HID * sizeof(float), stream);
        hipMemsetAsync(sumexp, 0, (size_t)NN * 8 * sizeof(float), stream);
    }

    prep_kernel<<<7018 + (NT * NE + 255) / 256, 256, 0, stream>>>(
        x, Wq, Wk, Wm, Xbf, Wtb, a0, a1, a2, counts);
    scan_kernel<<<1, 1024, 0, stream>>>(counts, offsets, cursors);
    scatter_kernel<<<(NT * NE + 255) / 256, 256, 0, stream>>>(a0, a1, a2, cursors, edata);

    const int gx = (NN + 127) / 128;    // 391
    const int gb = (NN + 3) / 4;        // 12500
    if (fused) {
        gemm_kernel<<<dim3(gx, 12), 256, 0, stream>>>(Xbf, Wtb, bm, P, 0, 1);
        gather_kernel<<<gb, 256, 0, stream>>>(P, offsets, counts, edata,
                                              out, sumexp, 0, 3, 2, 1);
    } else {
        for (int t = 0; t < NT; ++t) {
            gemm_kernel<<<dim3(gx, 4), 256, 0, stream>>>(Xbf, Wtb, bm, P, t, 0);
            gather_kernel<<<gb, 256, 0, stream>>>(P, offsets, counts, edata,
                                                  out, sumexp, t, 1, t == 2 ? 1 : 0, 0);
        }
    }
}

// Round 7
// 341.948 us; speedup vs baseline: 1.9432x; 1.9432x over previous
//
#include <hip/hip_runtime.h>

#define HID 128
#define NE 250000
#define NT 3
#define NN 50000
#define NSEG (NT * NN)          // 150000 segments (type-major)
#define NB1 586                 // ceil(NSEG/256)
#define BPAD 136                // LDS W row stride in halves (272B: 16B-aligned, 2-way banks)
#define PLANE (NN * 256)        // u16 elems per combined plane (512 B rows)

typedef unsigned int u32;
typedef unsigned short u16;
typedef __attribute__((ext_vector_type(8))) short short8;
typedef __attribute__((ext_vector_type(4))) float f32x4;

__device__ __forceinline__ u16 f2bf(float f) {
    u32 u = __float_as_uint(f);
    u += 0x7fffu + ((u >> 16) & 1u);      // RNE, inputs finite
    return (u16)(u >> 16);
}
__device__ __forceinline__ float bflo(u32 u) { return __uint_as_float(u << 16); }
__device__ __forceinline__ float bfhi(u32 u) { return __uint_as_float(u & 0xffff0000u); }

// ---- prep: xbf convert | W transpose+convert | CSR degree count, one dispatch
__global__ __launch_bounds__(256)
void prep_kernel(const float* __restrict__ x,
                 const float* __restrict__ Wq, const float* __restrict__ Wk,
                 const float* __restrict__ Wm,
                 u16* __restrict__ Xbf, u16* __restrict__ Wtb,
                 const int* __restrict__ a0, const int* __restrict__ a1,
                 const int* __restrict__ a2, u32* __restrict__ counts)
{
    const int b = blockIdx.x, tid = threadIdx.x;
    if (b < 6250) {                       // x -> bf16, 1,600,000 float4 exactly
        const int gid = b * 256 + tid;
        const float4 v = ((const float4*)x)[gid];
        ushort4 o;
        o.x = f2bf(v.x); o.y = f2bf(v.y); o.z = f2bf(v.z); o.w = f2bf(v.w);
        ((ushort4*)Xbf)[gid] = o;
    } else if (b < 7018) {                // W -> Wtb[mat][n][k] bf16, 196,608 exactly
        const int gid = (b - 6250) * 256 + tid;
        const int mat = gid >> 14;
        const int i   = gid & 16383;      // i = k*128 + n
        const int k   = i >> 7;
        const int n   = i & 127;
        const int t   = mat >> 2;
        const int m   = mat & 3;
        const float* src;
        if (m == 0)      src = Wq + (size_t)t * 16384;
        else if (m == 1) src = Wk + (size_t)t * 16384;
        else if (m == 2) src = Wm + (size_t)t * 32768;
        else             src = Wm + (size_t)t * 32768 + 16384;
        Wtb[(size_t)mat * 16384 + n * HID + k] = f2bf(src[i]);
    } else {                              // degree count
        const int gid = (b - 7018) * 256 + tid;
        if (gid >= NT * NE) return;
        const int t = gid / NE, e = gid - t * NE;
        const int* adj = (t == 0) ? a0 : (t == 1) ? a1 : a2;
        atomicAdd(&counts[t * NN + adj[2 * e + 1]], 1u);
    }
}

// ---- CSR scan (3-stage, coalesced & parallel — R5-proven) / scatter
__global__ __launch_bounds__(256)
void scan1_kernel(const u32* __restrict__ counts, u32* __restrict__ bsum)
{
    __shared__ u32 s[256];
    const int tid = threadIdx.x;
    const int idx = blockIdx.x * 256 + tid;
    s[tid] = (idx < NSEG) ? counts[idx] : 0u;
    __syncthreads();
    for (int st = 128; st > 0; st >>= 1) {
        if (tid < st) s[tid] += s[tid + st];
        __syncthreads();
    }
    if (tid == 0) bsum[blockIdx.x] = s[0];
}

__global__ __launch_bounds__(1024)
void scan2_kernel(u32* __restrict__ bsum)
{
    __shared__ u32 s[1024];
    const int tid = threadIdx.x;
    const u32 v = (tid < NB1) ? bsum[tid] : 0u;
    s[tid] = v;
    __syncthreads();
    for (int st = 1; st < 1024; st <<= 1) {
        const u32 a = (tid >= st) ? s[tid - st] : 0u;
        __syncthreads();
        s[tid] += a;
        __syncthreads();
    }
    if (tid < NB1) bsum[tid] = s[tid] - v;
}

__global__ __launch_bounds__(256)
void scan3_kernel(const u32* __restrict__ counts, const u32* __restrict__ bsum,
                  u32* __restrict__ offsets, u32* __restrict__ cursors)
{
    __shared__ u32 s[256];
    const int tid = threadIdx.x;
    const int idx = blockIdx.x * 256 + tid;
    const u32 v = (idx < NSEG) ? counts[idx] : 0u;
    s[tid] = v;
    __syncthreads();
    for (int st = 1; st < 256; st <<= 1) {
        const u32 a = (tid >= st) ? s[tid - st] : 0u;
        __syncthreads();
        s[tid] += a;
        __syncthreads();
    }
    if (idx < NSEG) {
        const u32 off = bsum[blockIdx.x] + s[tid] - v;
        offsets[idx] = off;
        cursors[idx] = off;
    }
}

__global__ __launch_bounds__(256)
void scatter_kernel(const int* __restrict__ a0, const int* __restrict__ a1,
                    const int* __restrict__ a2, u32* __restrict__ cursors,
                    u32* __restrict__ edata)
{
    const int gid = blockIdx.x * 256 + threadIdx.x;
    if (gid >= NT * NE) return;
    const int t = gid / NE, e = gid - t * NE;
    const int* adj = (t == 0) ? a0 : (t == 1) ? a1 : a2;
    const int src = adj[2 * e];
    const int tgt = adj[2 * e + 1];
    const u32 pos = atomicAdd(&cursors[t * NN + tgt], 1u);
    edata[pos] = (u32)src;
}

// ---- MFMA gemm, transposed orientation: D = W^T (A) x X^T (B)
// C/D: n=lane&15 -> node, row=quad*4+reg -> outcol => lane holds 4 consecutive
// outcols of ONE node. Interleaved plane layout: node row = 512 B, group g holds
// {slot0: cols 2g,2g+1 of k|q, slot1: cols 2g,2g+1 of a|b} as 2 u32s.
__global__ __launch_bounds__(256)
void gemm_kernel(const u16* __restrict__ Xbf, const u16* __restrict__ Wtb,
                 const float* __restrict__ bm, u16* __restrict__ P,
                 int tbase, int fusedF)
{
    __shared__ u16 Ws[128 * BPAD];        // 34,816 B
    const int tid = threadIdx.x;
    const int by  = blockIdx.y;
    const int mat = tbase * 4 + by;
    const int t   = mat >> 2, m = mat & 3;
    const u16* Wt = Wtb + (size_t)mat * 16384;

    for (int c = tid; c < 2048; c += 256) {
        const int r = c >> 4, s = (c & 15) * 8;
        *(short8*)&Ws[r * BPAD + s] = *(const short8*)(Wt + r * HID + s);
    }
    __syncthreads();

    const int wave = tid >> 6, lane = tid & 63;
    const int lm = lane & 15, quad = lane >> 4;
    const int r0 = blockIdx.x * 128 + wave * 32;
    const int ar0 = min(r0 + lm,      NN - 1);   // clamp; stores guarded
    const int ar1 = min(r0 + 16 + lm, NN - 1);

    f32x4 acc[8][2];
    #pragma unroll
    for (int ct = 0; ct < 8; ++ct) {
        acc[ct][0] = (f32x4){0.f, 0.f, 0.f, 0.f};
        acc[ct][1] = (f32x4){0.f, 0.f, 0.f, 0.f};
    }

    for (int k0 = 0; k0 < HID; k0 += 32) {
        // B-frag (X^T): n=node=lane&15, k=quad*8+j -> contiguous in Xbf[node]
        const short8 X0 = *(const short8*)(Xbf + (size_t)ar0 * HID + k0 + quad * 8);
        const short8 X1 = *(const short8*)(Xbf + (size_t)ar1 * HID + k0 + quad * 8);
        #pragma unroll
        for (int ct = 0; ct < 8; ++ct) {
            // A-frag (W^T): m=outcol=lane&15, k=quad*8+j -> contiguous in Wtb[n][k]
            const short8 Wf = *(const short8*)&Ws[(ct * 16 + lm) * BPAD + k0 + quad * 8];
            acc[ct][0] = __builtin_amdgcn_mfma_f32_16x16x32_bf16(Wf, X0, acc[ct][0], 0, 0, 0);
            acc[ct][1] = __builtin_amdgcn_mfma_f32_16x16x32_bf16(Wf, X1, acc[ct][1], 0, 0, 0);
        }
    }

    const int slot = (m == 2 || m == 3) ? 2 : 0;                   // a,b -> slot 1
    const int pidx = (m == 1 || m == 2) ? (fusedF ? t : 0)         // KA plane
                                        : (fusedF ? (3 + t) : 1);  // QB plane
    u16* Pd = P + (size_t)pidx * PLANE + slot;
    #pragma unroll
    for (int ct = 0; ct < 8; ++ct) {
        const int oc = ct * 16 + quad * 4;           // this lane's 4 outcols
        const int g0 = oc >> 1;                      // group of (oc,oc+1)
        float b0 = 0.f, b1 = 0.f, b2 = 0.f, b3 = 0.f;
        if (m == 3) {
            const float4 bv = *(const float4*)(bm + t * HID + oc);
            b0 = bv.x; b1 = bv.y; b2 = bv.z; b3 = bv.w;
        }
        #pragma unroll
        for (int nt = 0; nt < 2; ++nt) {
            const int node = r0 + nt * 16 + lm;
            if (node < NN) {
                u16* rowp = Pd + (size_t)node * 256;
                *(u32*)(rowp + g0 * 4) =
                    (u32)f2bf(acc[ct][nt][0] + b0) | ((u32)f2bf(acc[ct][nt][1] + b1) << 16);
                *(u32*)(rowp + (g0 + 1) * 4) =
                    (u32)f2bf(acc[ct][nt][2] + b2) | ((u32)f2bf(acc[ct][nt][3] + b3) << 16);
            }
        }
    }
}

// ---- gather: one wave per node; loops ntypes types, acc/den in registers.
// mode: 0 = accumulate (RMW out + sumexp), 1 = final using sumexp, 2 = final pure
__global__ __launch_bounds__(256)
void gather_kernel(const u16* __restrict__ P, const u32* __restrict__ offsets,
                   const u32* __restrict__ counts, const u32* __restrict__ edata,
                   float* __restrict__ out, float* __restrict__ sumexp,
                   int tbase, int ntypes, int mode, int fusedF)
{
    const int wave = threadIdx.x >> 6, lane = threadIdx.x & 63;
    const int node = blockIdx.x * 4 + wave;
    if (node >= NN) return;
    const int h = lane >> 3;

    float acc0 = 0.f, acc1 = 0.f, den = 0.f;
    int degtot = 0;

    for (int tt = 0; tt < ntypes; ++tt) {
        const u16* KA = P + (size_t)(fusedF ? tt : 0) * PLANE;
        const u16* QB = P + (size_t)(fusedF ? (3 + tt) : 1) * PLANE;
        const int seg   = (tbase + tt) * NN + node;
        const u32 start = offsets[seg];
        const int deg   = (int)counts[seg];
        degtot += deg;
        if (deg == 0) continue;

        const uint2 qbv = *(const uint2*)(QB + (size_t)node * 256 + lane * 4);
        const float q0 = bflo(qbv.x) * 0.25f, q1 = bfhi(qbv.x) * 0.25f;  // fold PHD^-0.5
        const float b0 = bflo(qbv.y), b1 = bfhi(qbv.y);

        for (int e = 0; e < deg; e += 4) {           // clamped-tail uniform loop
            uint2 kav[4];
            float w[4];
            #pragma unroll
            for (int u = 0; u < 4; ++u) {
                const int idx = min(e + u, deg - 1);
                const int src = __builtin_amdgcn_readfirstlane((int)edata[start + idx]);
                kav[u] = *(const uint2*)(KA + (size_t)src * 256 + lane * 4);
                w[u] = (e + u < deg) ? 1.f : 0.f;
            }
            #pragma unroll
            for (int u = 0; u < 4; ++u) {
                float d = q0 * bflo(kav[u].x) + q1 * bfhi(kav[u].x);
                d += __shfl_xor(d, 1);
                d += __shfl_xor(d, 2);
                d += __shfl_xor(d, 4);
                const float ex = __expf(d) * w[u];
                acc0 += ex * fmaxf(bflo(kav[u].y) + b0, 0.f);
                acc1 += ex * fmaxf(bfhi(kav[u].y) + b1, 0.f);
                den  += ex;
            }
        }
    }

    float* op = out + (size_t)node * HID + lane * 2;
    if (mode == 2) {                       // fused: softmax over all 3 types in-register
        const float inv = den > 0.f ? 1.f / den : 0.f;
        float2 o;
        o.x = acc0 * inv;
        o.y = acc1 * inv;
        *(float2*)op = o;
    } else if (mode == 1) {
        const float tot = sumexp[(size_t)node * 8 + h] + den;
        const float inv = tot > 0.f ? 1.f / tot : 0.f;
        float2 o = *(float2*)op;
        o.x = (o.x + acc0) * inv;
        o.y = (o.y + acc1) * inv;
        *(float2*)op = o;
    } else {
        if (degtot == 0) return;
        float2 o = *(float2*)op;
        o.x += acc0; o.y += acc1;
        *(float2*)op = o;
        if ((lane & 7) == 0) sumexp[(size_t)node * 8 + h] += den;
    }
}

extern "C" void kernel_launch(void* const* d_in, const int* in_sizes, int n_in,
                              void* d_out, int out_size, void* d_ws, size_t ws_size,
                              hipStream_t stream)
{
    const float* x  = (const float*)d_in[0];
    const int* a0   = (const int*)d_in[1];
    const int* a1   = (const int*)d_in[2];
    const int* a2   = (const int*)d_in[3];
    const float* Wq = (const float*)d_in[4];
    const float* Wk = (const float*)d_in[5];
    const float* Wm = (const float*)d_in[6];
    const float* bm = (const float*)d_in[7];
    float* out = (float*)d_out;

    // ws layout; fused path: 6 combined planes (153.6 MB), fallback: 2 (51.2 MB).
    const size_t planeB = (size_t)PLANE * sizeof(u16);       // 25.6 MB
    const size_t fixedB = 12800000 + 393216 + 3 * 600000 + 4096 + 3000000 + 1600000;
    const int fused = (ws_size >= 6 * planeB + fixedB) ? 1 : 0;
    const int npl = fused ? 6 : 2;

    char* p = (char*)d_ws;
    u16* P        = (u16*)p;            p += (size_t)npl * planeB;
    u16* Xbf      = (u16*)p;            p += 12800000;
    u16* Wtb      = (u16*)p;            p += 393216;
    u32* counts   = (u32*)p;            p += 600000;
    u32* offsets  = (u32*)p;            p += 600000;
    u32* cursors  = (u32*)p;            p += 600000;
    u32* bsum     = (u32*)p;            p += 4096;
    u32* edata    = (u32*)p;            p += 3000000;
    float* sumexp = (float*)p;

    hipMemsetAsync(counts, 0, (size_t)NSEG * sizeof(u32), stream);
    if (!fused) {
        hipMemsetAsync(out,    0, (size_t)NN * HID * sizeof(float), stream);
        hipMemsetAsync(sumexp, 0, (size_t)NN * 8 * sizeof(float), stream);
    }

    prep_kernel<<<7018 + (NT * NE + 255) / 256, 256, 0, stream>>>(
        x, Wq, Wk, Wm, Xbf, Wtb, a0, a1, a2, counts);
    scan1_kernel<<<NB1, 256, 0, stream>>>(counts, bsum);
    scan2_kernel<<<1, 1024, 0, stream>>>(bsum);
    scan3_kernel<<<NB1, 256, 0, stream>>>(counts, bsum, offsets, cursors);
    scatter_kernel<<<(NT * NE + 255) / 256, 256, 0, stream>>>(a0, a1, a2, cursors, edata);

    const int gx = (NN + 127) / 128;    // 391
    const int gb = (NN + 3) / 4;        // 12500
    if (fused) {
        gemm_kernel<<<dim3(gx, 12), 256, 0, stream>>>(Xbf, Wtb, bm, P, 0, 1);
        gather_kernel<<<gb, 256, 0, stream>>>(P, offsets, counts, edata,
                                              out, sumexp, 0, 3, 2, 1);
    } else {
        for (int t = 0; t < NT; ++t) {
            gemm_kernel<<<dim3(gx, 4), 256, 0, stream>>>(Xbf, Wtb, bm, P, t, 0);
            gather_kernel<<<gb, 256, 0, stream>>>(P, offsets, counts, edata,
                                                  out, sumexp, t, 1, t == 2 ? 1 : 0, 0);
        }
    }
}

// Round 8
// 321.990 us; speedup vs baseline: 2.0637x; 1.0620x over previous
//
#include <hip/hip_runtime.h>

#define HID 128
#define NE 250000
#define NT 3
#define NN 50000
#define NSEG (NT * NN)          // 150000 segments (type-major)
#define NB1 586                 // ceil(NSEG/256)
#define BPAD 136                // LDS W row stride in halves (272B: 16B-aligned, 2-way banks)
#define PLANE (NN * 256)        // u16 elems per combined plane (512 B rows)
#define OPAD 132                // LDS out-row stride in dwords (2-way banks)

typedef unsigned int u32;
typedef unsigned short u16;
typedef __attribute__((ext_vector_type(8))) short short8;
typedef __attribute__((ext_vector_type(4))) float f32x4;

__device__ __forceinline__ u16 f2bf(float f) {
    u32 u = __float_as_uint(f);
    u += 0x7fffu + ((u >> 16) & 1u);      // RNE, inputs finite
    return (u16)(u >> 16);
}
__device__ __forceinline__ float bflo(u32 u) { return __uint_as_float(u << 16); }
__device__ __forceinline__ float bfhi(u32 u) { return __uint_as_float(u & 0xffff0000u); }

// ---- prep: xbf convert | W transpose+convert | CSR degree count, one dispatch
__global__ __launch_bounds__(256)
void prep_kernel(const float* __restrict__ x,
                 const float* __restrict__ Wq, const float* __restrict__ Wk,
                 const float* __restrict__ Wm,
                 u16* __restrict__ Xbf, u16* __restrict__ Wtb,
                 const int* __restrict__ a0, const int* __restrict__ a1,
                 const int* __restrict__ a2, u32* __restrict__ counts)
{
    const int b = blockIdx.x, tid = threadIdx.x;
    if (b < 6250) {                       // x -> bf16, 1,600,000 float4 exactly
        const int gid = b * 256 + tid;
        const float4 v = ((const float4*)x)[gid];
        ushort4 o;
        o.x = f2bf(v.x); o.y = f2bf(v.y); o.z = f2bf(v.z); o.w = f2bf(v.w);
        ((ushort4*)Xbf)[gid] = o;
    } else if (b < 7018) {                // W -> Wtb[mat][n][k] bf16, 196,608 exactly
        const int gid = (b - 6250) * 256 + tid;
        const int mat = gid >> 14;
        const int i   = gid & 16383;      // i = k*128 + n
        const int k   = i >> 7;
        const int n   = i & 127;
        const int t   = mat >> 2;
        const int m   = mat & 3;
        const float* src;
        if (m == 0)      src = Wq + (size_t)t * 16384;
        else if (m == 1) src = Wk + (size_t)t * 16384;
        else if (m == 2) src = Wm + (size_t)t * 32768;
        else             src = Wm + (size_t)t * 32768 + 16384;
        Wtb[(size_t)mat * 16384 + n * HID + k] = f2bf(src[i]);
    } else {                              // degree count
        const int gid = (b - 7018) * 256 + tid;
        if (gid >= NT * NE) return;
        const int t = gid / NE, e = gid - t * NE;
        const int* adj = (t == 0) ? a0 : (t == 1) ? a1 : a2;
        atomicAdd(&counts[t * NN + adj[2 * e + 1]], 1u);
    }
}

// ---- CSR scan (3-stage, coalesced & parallel) / scatter
__global__ __launch_bounds__(256)
void scan1_kernel(const u32* __restrict__ counts, u32* __restrict__ bsum)
{
    __shared__ u32 s[256];
    const int tid = threadIdx.x;
    const int idx = blockIdx.x * 256 + tid;
    s[tid] = (idx < NSEG) ? counts[idx] : 0u;
    __syncthreads();
    for (int st = 128; st > 0; st >>= 1) {
        if (tid < st) s[tid] += s[tid + st];
        __syncthreads();
    }
    if (tid == 0) bsum[blockIdx.x] = s[0];
}

__global__ __launch_bounds__(1024)
void scan2_kernel(u32* __restrict__ bsum)
{
    __shared__ u32 s[1024];
    const int tid = threadIdx.x;
    const u32 v = (tid < NB1) ? bsum[tid] : 0u;
    s[tid] = v;
    __syncthreads();
    for (int st = 1; st < 1024; st <<= 1) {
        const u32 a = (tid >= st) ? s[tid - st] : 0u;
        __syncthreads();
        s[tid] += a;
        __syncthreads();
    }
    if (tid < NB1) bsum[tid] = s[tid] - v;
}

__global__ __launch_bounds__(256)
void scan3_kernel(const u32* __restrict__ counts, const u32* __restrict__ bsum,
                  u32* __restrict__ offsets, u32* __restrict__ cursors)
{
    __shared__ u32 s[256];
    const int tid = threadIdx.x;
    const int idx = blockIdx.x * 256 + tid;
    const u32 v = (idx < NSEG) ? counts[idx] : 0u;
    s[tid] = v;
    __syncthreads();
    for (int st = 1; st < 256; st <<= 1) {
        const u32 a = (tid >= st) ? s[tid - st] : 0u;
        __syncthreads();
        s[tid] += a;
        __syncthreads();
    }
    if (idx < NSEG) {
        const u32 off = bsum[blockIdx.x] + s[tid] - v;
        offsets[idx] = off;
        cursors[idx] = off;
    }
}

__global__ __launch_bounds__(256)
void scatter_kernel(const int* __restrict__ a0, const int* __restrict__ a1,
                    const int* __restrict__ a2, u32* __restrict__ cursors,
                    u32* __restrict__ edata)
{
    const int gid = blockIdx.x * 256 + threadIdx.x;
    if (gid >= NT * NE) return;
    const int t = gid / NE, e = gid - t * NE;
    const int* adj = (t == 0) ? a0 : (t == 1) ? a1 : a2;
    const int src = adj[2 * e];
    const int tgt = adj[2 * e + 1];
    const u32 pos = atomicAdd(&cursors[t * NN + tgt], 1u);
    edata[pos] = (u32)src;
}

// ---- MFMA gemm: one block = 64 nodes of ONE combined plane (both matrices).
// D = W^T (A) x X^T (B); C/D: n=lane&15 -> node, row=quad*4+reg -> outcol.
// Interleaved row image (group g: {slot0 cols 2g,2g+1; slot1 cols 2g,2g+1})
// built in padded LDS, then streamed out as dense full-line dwordx4 stores.
__global__ __launch_bounds__(256)
void gemm_kernel(const u16* __restrict__ Xbf, const u16* __restrict__ Wtb,
                 const float* __restrict__ bm, u16* __restrict__ P,
                 int tbase, int fusedF)
{
    __shared__ u32 lds_u[17408];          // 69,632 B: union{ Ws[2][128*BPAD]u16, Os[64*OPAD]u32 }
    u16* Ws = (u16*)lds_u;
    const int tid = threadIdx.x;
    const int by  = blockIdx.y;

    int pidx, type, isQB;
    if (fusedF) { pidx = by; isQB = (by >= 3); type = isQB ? by - 3 : by; }
    else        { pidx = by; isQB = by;        type = tbase; }
    const int mat0 = type * 4 + (isQB ? 0 : 1);   // slot0: q | k
    const int mat1 = type * 4 + (isQB ? 3 : 2);   // slot1: b(+bias) | a

    // stage both W matrices (each 128 rows x 128 u16) into padded LDS
    for (int c = tid; c < 4096; c += 256) {
        const int mloc = c >> 11;
        const int c2   = c & 2047;
        const int r = c2 >> 4, s = (c2 & 15) * 8;
        const int mat = mloc ? mat1 : mat0;
        *(short8*)&Ws[mloc * 128 * BPAD + r * BPAD + s] =
            *(const short8*)(Wtb + (size_t)mat * 16384 + r * HID + s);
    }
    __syncthreads();

    const int wave = tid >> 6, lane = tid & 63;
    const int lm = lane & 15, quad = lane >> 4;
    const int n0 = blockIdx.x * 64;
    const int ar = min(n0 + wave * 16 + lm, NN - 1);   // clamp; out-write guarded

    f32x4 acc[2][8];
    #pragma unroll
    for (int s = 0; s < 2; ++s)
        #pragma unroll
        for (int ct = 0; ct < 8; ++ct)
            acc[s][ct] = (f32x4){0.f, 0.f, 0.f, 0.f};

    for (int k0 = 0; k0 < HID; k0 += 32) {
        // B-frag (X^T): n=node=lane&15, k=quad*8+j — contiguous in Xbf[node]
        const short8 X = *(const short8*)(Xbf + (size_t)ar * HID + k0 + quad * 8);
        #pragma unroll
        for (int ct = 0; ct < 8; ++ct) {
            // A-frag (W^T): m=outcol=lane&15, k=quad*8+j
            const short8 W0 = *(const short8*)&Ws[(ct * 16 + lm) * BPAD + k0 + quad * 8];
            const short8 W1 = *(const short8*)&Ws[128 * BPAD + (ct * 16 + lm) * BPAD + k0 + quad * 8];
            acc[0][ct] = __builtin_amdgcn_mfma_f32_16x16x32_bf16(W0, X, acc[0][ct], 0, 0, 0);
            acc[1][ct] = __builtin_amdgcn_mfma_f32_16x16x32_bf16(W1, X, acc[1][ct], 0, 0, 0);
        }
    }
    __syncthreads();                      // all waves done reading Ws; reuse LDS as Os

    u32* Os = lds_u;
    const int nl = wave * 16 + lm;        // node-local row 0..63
    #pragma unroll
    for (int ct = 0; ct < 8; ++ct) {
        const int oc = ct * 16 + quad * 4;           // this lane's 4 outcols
        const int g0 = oc >> 1;
        float b0 = 0.f, b1 = 0.f, b2 = 0.f, b3 = 0.f;
        if (isQB) {                                   // bias folds into slot1 (m==3)
            const float4 bv = *(const float4*)(bm + type * HID + oc);
            b0 = bv.x; b1 = bv.y; b2 = bv.z; b3 = bv.w;
        }
        Os[nl * OPAD + g0 * 2 + 0] =
            (u32)f2bf(acc[0][ct][0]) | ((u32)f2bf(acc[0][ct][1]) << 16);
        Os[nl * OPAD + (g0 + 1) * 2 + 0] =
            (u32)f2bf(acc[0][ct][2]) | ((u32)f2bf(acc[0][ct][3]) << 16);
        Os[nl * OPAD + g0 * 2 + 1] =
            (u32)f2bf(acc[1][ct][0] + b0) | ((u32)f2bf(acc[1][ct][1] + b1) << 16);
        Os[nl * OPAD + (g0 + 1) * 2 + 1] =
            (u32)f2bf(acc[1][ct][2] + b2) | ((u32)f2bf(acc[1][ct][3] + b3) << 16);
    }
    __syncthreads();

    // dense full-line writeout: 64 rows x 512 B contiguous
    u32* dst = (u32*)(P + (size_t)pidx * PLANE) + (size_t)n0 * 128;
    for (int i = tid * 4; i < 8192; i += 1024) {
        const int row = i >> 7, w = i & 127;
        if (n0 + row < NN)
            *(uint4*)&dst[i] = *(const uint4*)&Os[row * OPAD + w];
    }
}

// ---- gather: one wave per node; loops ntypes types, acc/den in registers.
// mode: 0 = accumulate (RMW out + sumexp), 1 = final using sumexp, 2 = final pure
__global__ __launch_bounds__(256)
void gather_kernel(const u16* __restrict__ P, const u32* __restrict__ offsets,
                   const u32* __restrict__ counts, const u32* __restrict__ edata,
                   float* __restrict__ out, float* __restrict__ sumexp,
                   int tbase, int ntypes, int mode, int fusedF)
{
    const int wave = threadIdx.x >> 6, lane = threadIdx.x & 63;
    const int node = blockIdx.x * 4 + wave;
    if (node >= NN) return;
    const int h = lane >> 3;

    float acc0 = 0.f, acc1 = 0.f, den = 0.f;
    int degtot = 0;

    for (int tt = 0; tt < ntypes; ++tt) {
        const u16* KA = P + (size_t)(fusedF ? tt : 0) * PLANE;
        const u16* QB = P + (size_t)(fusedF ? (3 + tt) : 1) * PLANE;
        const int seg   = (tbase + tt) * NN + node;
        const u32 start = offsets[seg];
        const int deg   = (int)counts[seg];
        degtot += deg;
        if (deg == 0) continue;

        const uint2 qbv = *(const uint2*)(QB + (size_t)node * 256 + lane * 4);
        const float q0 = bflo(qbv.x) * 0.25f, q1 = bfhi(qbv.x) * 0.25f;  // fold PHD^-0.5
        const float b0 = bflo(qbv.y), b1 = bfhi(qbv.y);

        for (int e = 0; e < deg; e += 4) {           // clamped-tail uniform loop
            uint2 kav[4];
            float w[4];
            #pragma unroll
            for (int u = 0; u < 4; ++u) {
                const int idx = min(e + u, deg - 1);
                const int src = __builtin_amdgcn_readfirstlane((int)edata[start + idx]);
                kav[u] = *(const uint2*)(KA + (size_t)src * 256 + lane * 4);
                w[u] = (e + u < deg) ? 1.f : 0.f;
            }
            #pragma unroll
            for (int u = 0; u < 4; ++u) {
                float d = q0 * bflo(kav[u].x) + q1 * bfhi(kav[u].x);
                d += __shfl_xor(d, 1);
                d += __shfl_xor(d, 2);
                d += __shfl_xor(d, 4);
                const float ex = __expf(d) * w[u];
                acc0 += ex * fmaxf(bflo(kav[u].y) + b0, 0.f);
                acc1 += ex * fmaxf(bfhi(kav[u].y) + b1, 0.f);
                den  += ex;
            }
        }
    }

    float* op = out + (size_t)node * HID + lane * 2;
    if (mode == 2) {                       // fused: softmax over all 3 types in-register
        const float inv = den > 0.f ? 1.f / den : 0.f;
        float2 o;
        o.x = acc0 * inv;
        o.y = acc1 * inv;
        *(float2*)op = o;
    } else if (mode == 1) {
        const float tot = sumexp[(size_t)node * 8 + h] + den;
        const float inv = tot > 0.f ? 1.f / tot : 0.f;
        float2 o = *(float2*)op;
        o.x = (o.x + acc0) * inv;
        o.y = (o.y + acc1) * inv;
        *(float2*)op = o;
    } else {
        if (degtot == 0) return;
        float2 o = *(float2*)op;
        o.x += acc0; o.y += acc1;
        *(float2*)op = o;
        if ((lane & 7) == 0) sumexp[(size_t)node * 8 + h] += den;
    }
}

extern "C" void kernel_launch(void* const* d_in, const int* in_sizes, int n_in,
                              void* d_out, int out_size, void* d_ws, size_t ws_size,
                              hipStream_t stream)
{
    const float* x  = (const float*)d_in[0];
    const int* a0   = (const int*)d_in[1];
    const int* a1   = (const int*)d_in[2];
    const int* a2   = (const int*)d_in[3];
    const float* Wq = (const float*)d_in[4];
    const float* Wk = (const float*)d_in[5];
    const float* Wm = (const float*)d_in[6];
    const float* bm = (const float*)d_in[7];
    float* out = (float*)d_out;

    // ws layout; fused path: 6 combined planes (153.6 MB), fallback: 2 (51.2 MB).
    const size_t planeB = (size_t)PLANE * sizeof(u16);       // 25.6 MB
    const size_t fixedB = 12800000 + 393216 + 3 * 600000 + 4096 + 3000000 + 1600000;
    const int fused = (ws_size >= 6 * planeB + fixedB) ? 1 : 0;
    const int npl = fused ? 6 : 2;

    char* p = (char*)d_ws;
    u16* P        = (u16*)p;            p += (size_t)npl * planeB;
    u16* Xbf      = (u16*)p;            p += 12800000;
    u16* Wtb      = (u16*)p;            p += 393216;
    u32* counts   = (u32*)p;            p += 600000;
    u32* offsets  = (u32*)p;            p += 600000;
    u32* cursors  = (u32*)p;            p += 600000;
    u32* bsum     = (u32*)p;            p += 4096;
    u32* edata    = (u32*)p;            p += 3000000;
    float* sumexp = (float*)p;

    hipMemsetAsync(counts, 0, (size_t)NSEG * sizeof(u32), stream);
    if (!fused) {
        hipMemsetAsync(out,    0, (size_t)NN * HID * sizeof(float), stream);
        hipMemsetAsync(sumexp, 0, (size_t)NN * 8 * sizeof(float), stream);
    }

    prep_kernel<<<7018 + (NT * NE + 255) / 256, 256, 0, stream>>>(
        x, Wq, Wk, Wm, Xbf, Wtb, a0, a1, a2, counts);
    scan1_kernel<<<NB1, 256, 0, stream>>>(counts, bsum);
    scan2_kernel<<<1, 1024, 0, stream>>>(bsum);
    scan3_kernel<<<NB1, 256, 0, stream>>>(counts, bsum, offsets, cursors);
    scatter_kernel<<<(NT * NE + 255) / 256, 256, 0, stream>>>(a0, a1, a2, cursors, edata);

    const int gx = (NN + 63) / 64;      // 782
    const int gb = (NN + 3) / 4;        // 12500
    if (fused) {
        gemm_kernel<<<dim3(gx, 6), 256, 0, stream>>>(Xbf, Wtb, bm, P, 0, 1);
        gather_kernel<<<gb, 256, 0, stream>>>(P, offsets, counts, edata,
                                              out, sumexp, 0, 3, 2, 1);
    } else {
        for (int t = 0; t < NT; ++t) {
            gemm_kernel<<<dim3(gx, 2), 256, 0, stream>>>(Xbf, Wtb, bm, P, t, 0);
            gather_kernel<<<gb, 256, 0, stream>>>(P, offsets, counts, edata,
                                                  out, sumexp, t, 1, t == 2 ? 1 : 0, 0);
        }
    }
}